// Round 1
// baseline (340.343 us; speedup 1.0000x reference)
//
#include <hip/hip_runtime.h>

// pen_loss: cost = sum_t mean_b( |a+delta|*p + 10*(relu(-d-a)*[t>=1] + relu(-d-x0p) + relu(x0p+d-10)) )
// x0p = exclusive prefix sum of delta along t. B=2^20, T=24. Memory-bound stream: 288 MiB read.

constexpr int TT = 24;          // time steps
constexpr float ML_C = 10.0f;
constexpr float A_PEN_C = 10.0f;

__global__ __launch_bounds__(256)
void pen_partial_kernel(const float* __restrict__ dout,
                        const float* __restrict__ vary,
                        float* __restrict__ partial,
                        int B, float invB) {
    const int tid = threadIdx.x;
    const int row = blockIdx.x * 256 + tid;
    float s = 0.0f;
    if (row < B) {
        const float4* o4 = reinterpret_cast<const float4*>(dout + (size_t)row * TT);
        const float4* v4 = reinterpret_cast<const float4*>(vary + (size_t)row * (2 * TT));
        float d[TT], p[TT], a[TT];
        #pragma unroll
        for (int i = 0; i < TT / 4; ++i) {
            float4 t4 = o4[i];
            d[4*i+0] = t4.x; d[4*i+1] = t4.y; d[4*i+2] = t4.z; d[4*i+3] = t4.w;
        }
        #pragma unroll
        for (int i = 0; i < TT / 4; ++i) {
            float4 t4 = v4[i];
            p[4*i+0] = t4.x; p[4*i+1] = t4.y; p[4*i+2] = t4.z; p[4*i+3] = t4.w;
        }
        #pragma unroll
        for (int i = 0; i < TT / 4; ++i) {
            float4 t4 = v4[TT / 4 + i];
            a[4*i+0] = t4.x; a[4*i+1] = t4.y; a[4*i+2] = t4.z; a[4*i+3] = t4.w;
        }
        float x0 = 0.0f;   // exclusive prefix sum of delta
        #pragma unroll
        for (int t = 0; t < TT; ++t) {
            const float dd = d[t];
            const float aa = a[t];
            float mv0 = fmaxf(-dd - aa, 0.0f);       // hinge == relu (hinge(0)=0=relu(0))
            if (t == 0) mv0 = 0.0f;                  // t_mask
            const float mx1 = fmaxf(-dd - x0, 0.0f);
            const float mv1 = fmaxf(x0 + dd - ML_C, 0.0f);
            s += fabsf(aa + dd) * p[t] + (mv0 + mx1 + mv1) * A_PEN_C;
            x0 += dd;
        }
    }
    // wave(64) shuffle reduce
    #pragma unroll
    for (int off = 32; off > 0; off >>= 1)
        s += __shfl_down(s, off, 64);
    __shared__ float ws[4];
    if ((tid & 63) == 0) ws[tid >> 6] = s;
    __syncthreads();
    if (tid == 0) {
        partial[blockIdx.x] = (ws[0] + ws[1] + ws[2] + ws[3]) * invB;
    }
}

__global__ __launch_bounds__(256)
void pen_final_reduce_kernel(const float* __restrict__ partial,
                             float* __restrict__ out, int n) {
    const int tid = threadIdx.x;
    float s = 0.0f;
    for (int i = tid; i < n; i += 256) s += partial[i];
    #pragma unroll
    for (int off = 32; off > 0; off >>= 1)
        s += __shfl_down(s, off, 64);
    __shared__ float ws[4];
    if ((tid & 63) == 0) ws[tid >> 6] = s;
    __syncthreads();
    if (tid == 0) out[0] = ws[0] + ws[1] + ws[2] + ws[3];
}

extern "C" void kernel_launch(void* const* d_in, const int* in_sizes, int n_in,
                              void* d_out, int out_size, void* d_ws, size_t ws_size,
                              hipStream_t stream) {
    const float* dout = (const float*)d_in[0];   // out:   (B, 24) f32
    const float* vary = (const float*)d_in[1];   // var_y: (B, 48) f32
    const int B = in_sizes[0] / TT;
    const int nblocks = (B + 255) / 256;         // 4096 for B=2^20
    float* partial = (float*)d_ws;               // nblocks floats of scratch

    pen_partial_kernel<<<nblocks, 256, 0, stream>>>(dout, vary, partial, B, 1.0f / (float)B);
    pen_final_reduce_kernel<<<1, 256, 0, stream>>>(partial, (float*)d_out, nblocks);
}